// Round 1
// baseline (2513.195 us; speedup 1.0000x reference)
//
#include <hip/hip_runtime.h>
#include <hip/hip_bf16.h>

#define N_NODES 100000
#define E_EDGES 1600000
#define NDOCS   20000
#define DRAW    300
#define DIN     768
#define DH      200
#define DOUT    8

// ---------------- degree / dinv ----------------
__global__ __launch_bounds__(256) void k_init_deg(float* deg) {
    int i = blockIdx.x * 256 + threadIdx.x;
    if (i < N_NODES) deg[i] = 1.0f;  // self-loop weight
}

__global__ __launch_bounds__(256) void k_deg_atomic(const int* __restrict__ col,
                                                    const float* __restrict__ ew,
                                                    float* __restrict__ deg) {
    int e = blockIdx.x * 256 + threadIdx.x;
    if (e < E_EDGES) atomicAdd(&deg[col[e]], ew[e]);
}

__global__ __launch_bounds__(256) void k_dinv(float* deg) {
    int i = blockIdx.x * 256 + threadIdx.x;
    if (i < N_NODES) deg[i] = rsqrtf(deg[i]);   // deg >= 1 always
}

// ---------------- b1c = lin_b @ w1 ----------------
__global__ __launch_bounds__(256) void k_b1c(const float* __restrict__ lin_b,
                                             const float* __restrict__ w1,
                                             float* __restrict__ b1c) {
    int j = threadIdx.x;
    if (j >= DH) return;
    float acc = 0.f;
    for (int k = 0; k < DIN; k++) acc += lin_b[k] * w1[k * DH + j];
    b1c[j] = acc;
}

// ---------------- generic fp32 tiled GEMM: C[M,Nc] = A[M,K](lda) @ B[K,Nc](ldb) (+bias) ----------------
template <bool BIAS>
__global__ __launch_bounds__(256) void k_gemm(const float* __restrict__ A, int lda,
                                              const float* __restrict__ B, int ldb,
                                              float* __restrict__ C, int ldc,
                                              int M, int Nc, int K,
                                              const float* __restrict__ bias) {
    const int BM = 64, BN = 64, BK = 16;
    __shared__ float As[BK][BM + 1];
    __shared__ float Bs[BK][BN + 1];
    int tid = threadIdx.x;
    int brow = blockIdx.x * BM;
    int bcol = blockIdx.y * BN;
    int tr = (tid / 16) * 4;
    int tc = (tid % 16) * 4;
    float acc[4][4] = {};

    // A-load mapping: each thread reads 4 consecutive K elements
    int ar = tid / 4;          // 0..63 row in tile
    int ac = (tid % 4) * 4;    // 0..12 col (k) start
    // B-load mapping: coalesced across columns
    int bkr = (tid / 64) * 4;  // 0..12
    int bcc = tid % 64;

    for (int k0 = 0; k0 < K; k0 += BK) {
        #pragma unroll
        for (int i = 0; i < 4; i++) {
            int gr = brow + ar, gc = k0 + ac + i;
            As[ac + i][ar] = (gr < M && gc < K) ? A[(size_t)gr * lda + gc] : 0.f;
        }
        #pragma unroll
        for (int i = 0; i < 4; i++) {
            int gr = k0 + bkr + i, gc = bcol + bcc;
            Bs[bkr + i][bcc] = (gr < K && gc < Nc) ? B[(size_t)gr * ldb + gc] : 0.f;
        }
        __syncthreads();
        #pragma unroll
        for (int kk = 0; kk < BK; kk++) {
            float a[4], b[4];
            #pragma unroll
            for (int i = 0; i < 4; i++) a[i] = As[kk][tr + i];
            #pragma unroll
            for (int j = 0; j < 4; j++) b[j] = Bs[kk][tc + j];
            #pragma unroll
            for (int i = 0; i < 4; i++)
                #pragma unroll
                for (int j = 0; j < 4; j++)
                    acc[i][j] += a[i] * b[j];
        }
        __syncthreads();
    }
    #pragma unroll
    for (int i = 0; i < 4; i++) {
        int gr = brow + tr + i;
        if (gr >= M) continue;
        #pragma unroll
        for (int j = 0; j < 4; j++) {
            int gc = bcol + tc + j;
            if (gc < Nc) {
                float v = acc[i][j];
                if (BIAS) v += bias[gc];
                C[(size_t)gr * ldc + gc] = v;
            }
        }
    }
}

// ---------------- x1 init: self-loop + b1 ----------------
__global__ __launch_bounds__(256) void k_init_x1(const float* __restrict__ h,
                                                 const float* __restrict__ dinv,
                                                 const float* __restrict__ b1,
                                                 float* __restrict__ x1) {
    long long gid = (long long)blockIdx.x * 256 + threadIdx.x;
    if (gid >= (long long)N_NODES * DH) return;
    int i = (int)(gid / DH);
    int d = (int)(gid % DH);
    float di = dinv[i];
    x1[gid] = h[gid] * di * di + b1[d];
}

// ---------------- layer-1 edge aggregation: one wave64 per edge ----------------
__global__ __launch_bounds__(256) void k_agg1(const int* __restrict__ row,
                                              const int* __restrict__ col,
                                              const float* __restrict__ ew,
                                              const float* __restrict__ dinv,
                                              const float* __restrict__ h,
                                              float* __restrict__ x1) {
    long long gt = (long long)blockIdx.x * 256 + threadIdx.x;
    int e = (int)(gt >> 6);
    int lane = (int)(gt & 63);
    if (e >= E_EDGES) return;
    int r = row[e], c = col[e];
    float norm = dinv[r] * ew[e] * dinv[c];
    const float* hr = h + (size_t)r * DH;
    float* xc = x1 + (size_t)c * DH;
    #pragma unroll
    for (int d0 = 0; d0 < DH; d0 += 64) {
        int d = d0 + lane;
        if (d < DH) atomicAdd(&xc[d], hr[d] * norm);
    }
}

// ---------------- g = relu(x1) @ w2 ----------------
__global__ __launch_bounds__(256) void k_relu_gemm_w2(const float* __restrict__ x1,
                                                      const float* __restrict__ w2,
                                                      float* __restrict__ g) {
    __shared__ float xs[32][DH + 1];
    __shared__ float ws2[DH * DOUT];
    int tid = threadIdx.x;
    int base_row = blockIdx.x * 32;
    for (int i = tid; i < DH * DOUT; i += 256) ws2[i] = w2[i];
    for (int i = tid; i < 32 * DH; i += 256) {
        int lr = i / DH, k = i % DH;
        int gr = base_row + lr;
        xs[lr][k] = (gr < N_NODES) ? fmaxf(x1[(size_t)gr * DH + k], 0.f) : 0.f;
    }
    __syncthreads();
    int lr = tid / DOUT, j = tid % DOUT;
    int gr = base_row + lr;
    if (gr >= N_NODES) return;
    float acc = 0.f;
    #pragma unroll 8
    for (int k = 0; k < DH; k++) acc += xs[lr][k] * ws2[k * DOUT + j];
    g[(size_t)gr * DOUT + j] = acc;
}

// ---------------- out init: self-loop + b2 ----------------
__global__ __launch_bounds__(256) void k_init_out(const float* __restrict__ g,
                                                  const float* __restrict__ dinv,
                                                  const float* __restrict__ b2,
                                                  float* __restrict__ out) {
    long long gid = (long long)blockIdx.x * 256 + threadIdx.x;
    if (gid >= (long long)N_NODES * DOUT) return;
    int i = (int)(gid / DOUT);
    int d = (int)(gid % DOUT);
    float di = dinv[i];
    out[gid] = g[gid] * di * di + b2[d];
}

// ---------------- layer-2 edge aggregation: 8 threads per edge ----------------
__global__ __launch_bounds__(256) void k_agg2(const int* __restrict__ row,
                                              const int* __restrict__ col,
                                              const float* __restrict__ ew,
                                              const float* __restrict__ dinv,
                                              const float* __restrict__ g,
                                              float* __restrict__ out) {
    long long gid = (long long)blockIdx.x * 256 + threadIdx.x;
    int e = (int)(gid >> 3);
    int j = (int)(gid & 7);
    if (e >= E_EDGES) return;
    int r = row[e], c = col[e];
    float norm = dinv[r] * ew[e] * dinv[c];
    atomicAdd(&out[(size_t)c * DOUT + j], g[(size_t)r * DOUT + j] * norm);
}

extern "C" void kernel_launch(void* const* d_in, const int* in_sizes, int n_in,
                              void* d_out, int out_size, void* d_ws, size_t ws_size,
                              hipStream_t stream) {
    const float* features = (const float*)d_in[0];
    const int*   ei       = (const int*)d_in[1];
    const float* ew       = (const float*)d_in[2];
    // d_in[3] = num_docs scalar (compile-time constant here)
    const float* lin_w    = (const float*)d_in[4];
    const float* lin_b    = (const float*)d_in[5];
    const float* w1       = (const float*)d_in[6];
    const float* b1       = (const float*)d_in[7];
    const float* w2       = (const float*)d_in[8];
    const float* b2       = (const float*)d_in[9];
    float* out = (float*)d_out;

    const int* row = ei;            // edge_index[0] = source
    const int* col = ei + E_EDGES;  // edge_index[1] = target

    // workspace layout (floats)
    float* ws   = (float*)d_ws;
    float* dinv = ws;                         // N
    float* W1c  = dinv + N_NODES;             // 300*200
    float* b1c  = W1c + DRAW * DH;            // 200 (padded to 256)
    float* h    = b1c + 256;                  // N*200
    float* x1   = h + (size_t)N_NODES * DH;   // N*200
    float* g    = x1 + (size_t)N_NODES * DH;  // N*8

    // 1..3: degree -> dinv
    k_init_deg<<<(N_NODES + 255) / 256, 256, 0, stream>>>(dinv);
    k_deg_atomic<<<(E_EDGES + 255) / 256, 256, 0, stream>>>(col, ew, dinv);
    k_dinv<<<(N_NODES + 255) / 256, 256, 0, stream>>>(dinv);

    // 4: W1c = lin_w @ w1   (300x768 @ 768x200)
    {
        dim3 grid((DRAW + 63) / 64, (DH + 63) / 64);
        k_gemm<false><<<grid, 256, 0, stream>>>(lin_w, DIN, w1, DH, W1c, DH,
                                                DRAW, DH, DIN, nullptr);
    }
    // 5: b1c = lin_b @ w1
    k_b1c<<<1, 256, 0, stream>>>(lin_b, w1, b1c);

    // 6: docs: h[:20000] = feat[:20000] @ w1
    {
        dim3 grid((NDOCS + 63) / 64, (DH + 63) / 64);
        k_gemm<false><<<grid, 256, 0, stream>>>(features, DIN, w1, DH, h, DH,
                                                NDOCS, DH, DIN, nullptr);
    }
    // 7: words: h[20000:] = feat[20000:, :300] @ W1c + b1c
    {
        dim3 grid((N_NODES - NDOCS + 63) / 64, (DH + 63) / 64);
        k_gemm<true><<<grid, 256, 0, stream>>>(features + (size_t)NDOCS * DIN, DIN,
                                               W1c, DH, h + (size_t)NDOCS * DH, DH,
                                               N_NODES - NDOCS, DH, DRAW, b1c);
    }

    // 8: x1 = h * dinv^2 + b1 (self-loop + bias)
    {
        long long tot = (long long)N_NODES * DH;
        k_init_x1<<<(int)((tot + 255) / 256), 256, 0, stream>>>(h, dinv, b1, x1);
    }
    // 9: edge aggregation layer 1
    {
        long long tot = (long long)E_EDGES * 64;
        k_agg1<<<(int)((tot + 255) / 256), 256, 0, stream>>>(row, col, ew, dinv, h, x1);
    }
    // 10: g = relu(x1) @ w2
    k_relu_gemm_w2<<<(N_NODES + 31) / 32, 256, 0, stream>>>(x1, w2, g);

    // 11: out = g * dinv^2 + b2
    {
        long long tot = (long long)N_NODES * DOUT;
        k_init_out<<<(int)((tot + 255) / 256), 256, 0, stream>>>(g, dinv, b2, out);
    }
    // 12: edge aggregation layer 2
    {
        long long tot = (long long)E_EDGES * DOUT;
        k_agg2<<<(int)((tot + 255) / 256), 256, 0, stream>>>(row, col, ew, dinv, g, out);
    }
}

// Round 2
// 1627.422 us; speedup vs baseline: 1.5443x; 1.5443x over previous
//
#include <hip/hip_runtime.h>
#include <hip/hip_bf16.h>

#define N_NODES 100000
#define E_EDGES 1600000
#define NDOCS   20000
#define DRAW    300
#define DIN     768
#define DH      200
#define DOUT    8

#define SCAN_BLOCKS ((N_NODES + 255) / 256)   // 391

// ---------------- CSR build ----------------
__global__ __launch_bounds__(256) void k_count(const int* __restrict__ col,
                                               int* __restrict__ cnt) {
    int e = blockIdx.x * 256 + threadIdx.x;
    if (e < E_EDGES) atomicAdd(&cnt[col[e]], 1);
}

// per-block exclusive scan; writes block totals to partial[]
__global__ __launch_bounds__(256) void k_scan1(const int* __restrict__ cnt,
                                               int* __restrict__ off,
                                               int* __restrict__ partial) {
    __shared__ int s[256];
    int tid = threadIdx.x;
    int i = blockIdx.x * 256 + tid;
    int v = (i < N_NODES) ? cnt[i] : 0;
    s[tid] = v;
    __syncthreads();
    #pragma unroll
    for (int o = 1; o < 256; o <<= 1) {
        int t = (tid >= o) ? s[tid - o] : 0;
        __syncthreads();
        s[tid] += t;
        __syncthreads();
    }
    if (i < N_NODES) off[i] = s[tid] - v;   // exclusive
    if (tid == 255) partial[blockIdx.x] = s[255];
}

// exclusive scan of SCAN_BLOCKS partials, in place (single block, 512 thr)
__global__ __launch_bounds__(512) void k_scan2(int* __restrict__ partial) {
    __shared__ int s[512];
    int tid = threadIdx.x;
    int v = (tid < SCAN_BLOCKS) ? partial[tid] : 0;
    s[tid] = v;
    __syncthreads();
    #pragma unroll
    for (int o = 1; o < 512; o <<= 1) {
        int t = (tid >= o) ? s[tid - o] : 0;
        __syncthreads();
        s[tid] += t;
        __syncthreads();
    }
    if (tid < SCAN_BLOCKS) partial[tid] = s[tid] - v;
}

// add block offsets; duplicate into cursor array; set off[N]
__global__ __launch_bounds__(256) void k_scan3(int* __restrict__ off,
                                               const int* __restrict__ partial,
                                               int* __restrict__ cur) {
    int i = blockIdx.x * 256 + threadIdx.x;
    if (i < N_NODES) {
        int v = off[i] + partial[blockIdx.x];
        off[i] = v;
        cur[i] = v;
    }
    if (i == 0) off[N_NODES] = E_EDGES;
}

__global__ __launch_bounds__(256) void k_scatter(const int* __restrict__ row,
                                                 const int* __restrict__ col,
                                                 const float* __restrict__ ew,
                                                 int* __restrict__ cur,
                                                 int* __restrict__ srcs,
                                                 float* __restrict__ wts) {
    int e = blockIdx.x * 256 + threadIdx.x;
    if (e >= E_EDGES) return;
    int c = col[e];
    int pos = atomicAdd(&cur[c], 1);
    srcs[pos] = row[e];
    wts[pos] = ew[e];
}

// dinv[n] = rsqrt(1 + sum of incoming ew)  (self-loop gives the +1)
__global__ __launch_bounds__(256) void k_dinv_csr(const int* __restrict__ off,
                                                  const float* __restrict__ wts,
                                                  float* __restrict__ dinv) {
    int n = blockIdx.x * 256 + threadIdx.x;
    if (n >= N_NODES) return;
    float s = 1.0f;
    int e1 = off[n + 1];
    for (int e = off[n]; e < e1; e++) s += wts[e];
    dinv[n] = rsqrtf(s);
}

// ---------------- b1c = lin_b @ w1 ----------------
__global__ __launch_bounds__(256) void k_b1c(const float* __restrict__ lin_b,
                                             const float* __restrict__ w1,
                                             float* __restrict__ b1c) {
    int j = threadIdx.x;
    if (j >= DH) return;
    float acc = 0.f;
    for (int k = 0; k < DIN; k++) acc += lin_b[k] * w1[k * DH + j];
    b1c[j] = acc;
}

// ---------------- generic fp32 tiled GEMM ----------------
template <bool BIAS>
__global__ __launch_bounds__(256) void k_gemm(const float* __restrict__ A, int lda,
                                              const float* __restrict__ B, int ldb,
                                              float* __restrict__ C, int ldc,
                                              int M, int Nc, int K,
                                              const float* __restrict__ bias) {
    const int BM = 64, BN = 64, BK = 16;
    __shared__ float As[BK][BM + 1];
    __shared__ float Bs[BK][BN + 1];
    int tid = threadIdx.x;
    int brow = blockIdx.x * BM;
    int bcol = blockIdx.y * BN;
    int tr = (tid / 16) * 4;
    int tc = (tid % 16) * 4;
    float acc[4][4] = {};

    int ar = tid / 4;
    int ac = (tid % 4) * 4;
    int bkr = (tid / 64) * 4;
    int bcc = tid % 64;

    for (int k0 = 0; k0 < K; k0 += BK) {
        #pragma unroll
        for (int i = 0; i < 4; i++) {
            int gr = brow + ar, gc = k0 + ac + i;
            As[ac + i][ar] = (gr < M && gc < K) ? A[(size_t)gr * lda + gc] : 0.f;
        }
        #pragma unroll
        for (int i = 0; i < 4; i++) {
            int gr = k0 + bkr + i, gc = bcol + bcc;
            Bs[bkr + i][bcc] = (gr < K && gc < Nc) ? B[(size_t)gr * ldb + gc] : 0.f;
        }
        __syncthreads();
        #pragma unroll
        for (int kk = 0; kk < BK; kk++) {
            float a[4], b[4];
            #pragma unroll
            for (int i = 0; i < 4; i++) a[i] = As[kk][tr + i];
            #pragma unroll
            for (int j = 0; j < 4; j++) b[j] = Bs[kk][tc + j];
            #pragma unroll
            for (int i = 0; i < 4; i++)
                #pragma unroll
                for (int j = 0; j < 4; j++)
                    acc[i][j] += a[i] * b[j];
        }
        __syncthreads();
    }
    #pragma unroll
    for (int i = 0; i < 4; i++) {
        int gr = brow + tr + i;
        if (gr >= M) continue;
        #pragma unroll
        for (int j = 0; j < 4; j++) {
            int gc = bcol + tc + j;
            if (gc < Nc) {
                float v = acc[i][j];
                if (BIAS) v += bias[gc];
                C[(size_t)gr * ldc + gc] = v;
            }
        }
    }
}

// ---------------- layer-1 CSR aggregation, fused self-loop + b1 ----------------
// one wave per node; 4 dims per lane (stride 64)
__global__ __launch_bounds__(256) void k_agg1_csr(const int* __restrict__ off,
                                                  const int* __restrict__ srcs,
                                                  const float* __restrict__ wts,
                                                  const float* __restrict__ dinv,
                                                  const float* __restrict__ h,
                                                  const float* __restrict__ b1,
                                                  float* __restrict__ x1) {
    int wid = threadIdx.x >> 6, lane = threadIdx.x & 63;
    int n = blockIdx.x * 4 + wid;   // N_NODES % 4 == 0
    float dn = dinv[n];
    float dn2 = dn * dn;
    const float* hn = h + (size_t)n * DH;
    float acc[4];
    #pragma unroll
    for (int k = 0; k < 4; k++) {
        int d = lane + 64 * k;
        acc[k] = (d < DH) ? hn[d] * dn2 + b1[d] : 0.f;
    }
    int e1 = off[n + 1];
    for (int e = off[n]; e < e1; e++) {
        int r = srcs[e];
        float norm = dinv[r] * wts[e] * dn;
        const float* hr = h + (size_t)r * DH;
        #pragma unroll
        for (int k = 0; k < 4; k++) {
            int d = lane + 64 * k;
            if (d < DH) acc[k] += hr[d] * norm;
        }
    }
    float* xn = x1 + (size_t)n * DH;
    #pragma unroll
    for (int k = 0; k < 4; k++) {
        int d = lane + 64 * k;
        if (d < DH) xn[d] = acc[k];
    }
}

// ---------------- g = relu(x1) @ w2 ----------------
__global__ __launch_bounds__(256) void k_relu_gemm_w2(const float* __restrict__ x1,
                                                      const float* __restrict__ w2,
                                                      float* __restrict__ g) {
    __shared__ float xs[32][DH + 1];
    __shared__ float ws2[DH * DOUT];
    int tid = threadIdx.x;
    int base_row = blockIdx.x * 32;
    for (int i = tid; i < DH * DOUT; i += 256) ws2[i] = w2[i];
    for (int i = tid; i < 32 * DH; i += 256) {
        int lr = i / DH, k = i % DH;
        int gr = base_row + lr;
        xs[lr][k] = (gr < N_NODES) ? fmaxf(x1[(size_t)gr * DH + k], 0.f) : 0.f;
    }
    __syncthreads();
    int lr = tid / DOUT, j = tid % DOUT;
    int gr = base_row + lr;
    if (gr >= N_NODES) return;
    float acc = 0.f;
    #pragma unroll 8
    for (int k = 0; k < DH; k++) acc += xs[lr][k] * ws2[k * DOUT + j];
    g[(size_t)gr * DOUT + j] = acc;
}

// ---------------- layer-2 CSR aggregation, fused self-loop + b2 ----------------
// 8 threads per node (one per output dim)
__global__ __launch_bounds__(256) void k_agg2_csr(const int* __restrict__ off,
                                                  const int* __restrict__ srcs,
                                                  const float* __restrict__ wts,
                                                  const float* __restrict__ dinv,
                                                  const float* __restrict__ g,
                                                  const float* __restrict__ b2,
                                                  float* __restrict__ out) {
    int t = blockIdx.x * 256 + threadIdx.x;
    int n = t >> 3, j = t & 7;
    if (n >= N_NODES) return;
    float dn = dinv[n];
    float acc = g[(size_t)n * DOUT + j] * dn * dn + b2[j];
    int e1 = off[n + 1];
    for (int e = off[n]; e < e1; e++) {
        int r = srcs[e];
        acc += g[(size_t)r * DOUT + j] * (dinv[r] * wts[e] * dn);
    }
    out[(size_t)n * DOUT + j] = acc;
}

extern "C" void kernel_launch(void* const* d_in, const int* in_sizes, int n_in,
                              void* d_out, int out_size, void* d_ws, size_t ws_size,
                              hipStream_t stream) {
    const float* features = (const float*)d_in[0];
    const int*   ei       = (const int*)d_in[1];
    const float* ew       = (const float*)d_in[2];
    const float* lin_w    = (const float*)d_in[4];
    const float* lin_b    = (const float*)d_in[5];
    const float* w1       = (const float*)d_in[6];
    const float* b1       = (const float*)d_in[7];
    const float* w2       = (const float*)d_in[8];
    const float* b2       = (const float*)d_in[9];
    float* out = (float*)d_out;

    const int* row = ei;            // source
    const int* col = ei + E_EDGES;  // target

    // workspace layout
    float* ws       = (float*)d_ws;
    float* dinv     = ws;                               // N
    int*   off      = (int*)(dinv + N_NODES);           // N+1 (pad to N+4)
    int*   cur      = off + N_NODES + 4;                // N   (aliases cnt)
    int*   partials = cur + N_NODES;                    // 512
    int*   srcs     = partials + 512;                   // E
    float* wts      = (float*)(srcs + E_EDGES);         // E
    float* W1c      = wts + E_EDGES;                    // DRAW*DH
    float* b1c      = W1c + DRAW * DH;                  // 256
    float* h        = b1c + 256;                        // N*DH
    float* x1       = h + (size_t)N_NODES * DH;         // N*DH
    float* g        = x1 + (size_t)N_NODES * DH;        // N*DOUT

    // ---- CSR build ----
    hipMemsetAsync(cur, 0, N_NODES * sizeof(int), stream);          // cnt = 0
    k_count<<<(E_EDGES + 255) / 256, 256, 0, stream>>>(col, cur);   // cnt
    k_scan1<<<SCAN_BLOCKS, 256, 0, stream>>>(cur, off, partials);
    k_scan2<<<1, 512, 0, stream>>>(partials);
    k_scan3<<<SCAN_BLOCKS, 256, 0, stream>>>(off, partials, cur);
    k_scatter<<<(E_EDGES + 255) / 256, 256, 0, stream>>>(row, col, ew, cur, srcs, wts);
    k_dinv_csr<<<SCAN_BLOCKS, 256, 0, stream>>>(off, wts, dinv);

    // ---- GEMMs ----
    {   // W1c = lin_w @ w1   (300x768 @ 768x200)
        dim3 grid((DRAW + 63) / 64, (DH + 63) / 64);
        k_gemm<false><<<grid, 256, 0, stream>>>(lin_w, DIN, w1, DH, W1c, DH,
                                                DRAW, DH, DIN, nullptr);
    }
    k_b1c<<<1, 256, 0, stream>>>(lin_b, w1, b1c);
    {   // docs: h[:20000] = feat[:20000] @ w1
        dim3 grid((NDOCS + 63) / 64, (DH + 63) / 64);
        k_gemm<false><<<grid, 256, 0, stream>>>(features, DIN, w1, DH, h, DH,
                                                NDOCS, DH, DIN, nullptr);
    }
    {   // words: h[20000:] = feat[20000:, :300] @ W1c + b1c
        dim3 grid((N_NODES - NDOCS + 63) / 64, (DH + 63) / 64);
        k_gemm<true><<<grid, 256, 0, stream>>>(features + (size_t)NDOCS * DIN, DIN,
                                               W1c, DH, h + (size_t)NDOCS * DH, DH,
                                               N_NODES - NDOCS, DH, DRAW, b1c);
    }

    // ---- layer 1 aggregation (fused self-loop + b1) ----
    k_agg1_csr<<<N_NODES / 4, 256, 0, stream>>>(off, srcs, wts, dinv, h, b1, x1);

    // ---- layer 2 ----
    k_relu_gemm_w2<<<(N_NODES + 31) / 32, 256, 0, stream>>>(x1, w2, g);
    k_agg2_csr<<<(N_NODES * DOUT + 255) / 256, 256, 0, stream>>>(off, srcs, wts, dinv,
                                                                 g, b2, out);
}